// Round 18
// baseline (67.149 us; speedup 1.0000x reference)
//
#include <hip/hip_runtime.h>

// Problem constants (from reference setup_inputs)
#define BB 4096   // batch
#define SS 256    // sequence length
#define FF 64     // features
#define GG 9      // 3*U gate width

#define NEG_LOG2E -1.4426950408889634f
#define TWO_LOG2E  2.8853900817779268f

typedef float f2 __attribute__((ext_vector_type(2)));

#if __has_builtin(__builtin_amdgcn_exp2f)
__device__ __forceinline__ float fast_exp2(float x) { return __builtin_amdgcn_exp2f(x); }
#else
__device__ __forceinline__ float fast_exp2(float x) { return exp2f(x); }
#endif
#if __has_builtin(__builtin_amdgcn_rcpf)
__device__ __forceinline__ float fast_rcp(float x) { return __builtin_amdgcn_rcpf(x); }
#else
__device__ __forceinline__ float fast_rcp(float x) { return 1.0f / x; }
#endif

// DPP helper: quad_perm (CTRL<0x100) and row ops (row_ror:N = 0x120+N).
template <int CTRL>
__device__ __forceinline__ float dpp_f(float v) {
  return __int_as_float(
      __builtin_amdgcn_mov_dpp(__float_as_int(v), CTRL, 0xF, 0xF, true));
}
// packed variant: 2 mov_dpp + one v_pk_add at the caller (f2 +=)
template <int CTRL>
__device__ __forceinline__ f2 dpp_f2(f2 v) {
  return (f2){dpp_f<CTRL>(v.x), dpp_f<CTRL>(v.y)};
}

// -----------------------------------------------------------------------------
// Fully fused GRU — R18 = R17 (52.55us) + packed-f2 reduce.
// R14's A/B established each scalar dpp-add costs ~4-5cy (mov_dpp + v_add
// unfused). R17's reduce unpacked the f2 gate-pair accumulators into 9
// scalars before the butterfly (18 instr/stage). R18 keeps them PACKED:
// per stage 4x(2 mov_dpp + 1 v_pk_add_f32) + 2 (scalar a8) = 14 instr;
// ror stages pack {az,ar}. Net -10 instr/step. Per-value reduction order
// unchanged (xor1 -> xor2 -> ror4 -> ror8) -> absmax stays 0.
// Everything else byte-identical to R17.
// -----------------------------------------------------------------------------
__global__ __launch_bounds__(64, 1) void fused_gru_kernel(
    const float* __restrict__ x,           // [B,S,F]
    const float* __restrict__ kernel_w,    // [F,9]
    const float* __restrict__ rec_kernel,  // [3,9]
    const float* __restrict__ bias,        // [2,9]
    const float* __restrict__ dense_w,     // [3,10]
    const float* __restrict__ dense_b,     // [10]
    float* __restrict__ out)               // [B,10]
{
  const int lane = threadIdx.x;        // 0..63
  const int fl   = lane & 15;          // feature-slot within the chain's row
  const int u    = lane & 3;           // gate-unit role within the quad
  const int uc   = (u < 3) ? u : 2;    // lane u==3: clamp unit role (benign)
  const int c    = blockIdx.x * 4 + (lane >> 4);   // chain (batch) id

  // ---- input-projection weights for this lane's 4 features (pre-scaled)
  f2 w01[4], w23[4], w45[4], w67[4];
  float w8[4];
#pragma unroll
  for (int e = 0; e < 4; ++e) {
    const float* kw = kernel_w + (fl * 4 + e) * GG;
    w01[e] = (f2){kw[0] * NEG_LOG2E, kw[1] * NEG_LOG2E};
    w23[e] = (f2){kw[2] * NEG_LOG2E, kw[3] * NEG_LOG2E};
    w45[e] = (f2){kw[4] * NEG_LOG2E, kw[5] * NEG_LOG2E};
    w67[e] = (f2){kw[6] * TWO_LOG2E, kw[7] * TWO_LOG2E};
    w8[e]  = kw[8] * TWO_LOG2E;
  }

  // input bias (+ recurrent bias folded for z/r gates — exact), pre-scaled
  // and SIXTEENTH'd (16-lane reduce restores exactly 1x).
  const float Q = 0.0625f;
  const f2 b01q = {(bias[0] + bias[GG + 0]) * NEG_LOG2E * Q,
                   (bias[1] + bias[GG + 1]) * NEG_LOG2E * Q};
  const f2 b23q = {(bias[2] + bias[GG + 2]) * NEG_LOG2E * Q,
                   (bias[3] + bias[GG + 3]) * NEG_LOG2E * Q};
  const f2 b45q = {(bias[4] + bias[GG + 4]) * NEG_LOG2E * Q,
                   (bias[5] + bias[GG + 5]) * NEG_LOG2E * Q};
  const f2 b67q = {bias[6] * TWO_LOG2E * Q, bias[7] * TWO_LOG2E * Q};
  const float b8q = bias[8] * TWO_LOG2E * Q;

  // recurrent weights for this lane's unit (pre-scaled); only the h-gate's
  // recurrent bias stays separate (it sits inside the r-multiplied term).
  float wz[3], wr[3], wh[3];
#pragma unroll
  for (int hh = 0; hh < 3; ++hh) {
    wz[hh] = rec_kernel[hh * GG + uc]     * NEG_LOG2E;
    wr[hh] = rec_kernel[hh * GG + 3 + uc] * NEG_LOG2E;
    wh[hh] = rec_kernel[hh * GG + 6 + uc] * TWO_LOG2E;
  }
  const float rbh = bias[GG + 6 + uc] * TWO_LOG2E;

  float h0 = 0.0f, h1 = 0.0f, h2 = 0.0f, hprev = 0.0f;

  // per-lane x pointer: row (c,s) = 16 float4s; this lane reads float4 #fl.
  const float4* pc = reinterpret_cast<const float4*>(x) + (size_t)c * SS * 16 + fl;

  // depth-8 register ring (32 VGPRs), named buffers, static indexing
  float4 X0, X1, X2, X3, X4, X5, X6, X7;

  auto step = [&](const float4 v) {
    // projection over this lane's 4 features (20 instrs, f2-packed)
    f2 a01 = b01q, a23 = b23q, a45 = b45q, a67 = b67q;
    float a8 = b8q;
    a01 = v.x * w01[0] + a01; a23 = v.x * w23[0] + a23;
    a45 = v.x * w45[0] + a45; a67 = v.x * w67[0] + a67;
    a8 = fmaf(v.x, w8[0], a8);
    a01 = v.y * w01[1] + a01; a23 = v.y * w23[1] + a23;
    a45 = v.y * w45[1] + a45; a67 = v.y * w67[1] + a67;
    a8 = fmaf(v.y, w8[1], a8);
    a01 = v.z * w01[2] + a01; a23 = v.z * w23[2] + a23;
    a45 = v.z * w45[2] + a45; a67 = v.z * w67[2] + a67;
    a8 = fmaf(v.z, w8[2], a8);
    a01 = v.w * w01[3] + a01; a23 = v.w * w23[3] + a23;
    a45 = v.w * w45[3] + a45; a67 = v.w * w67[3] + a67;
    a8 = fmaf(v.w, w8[3], a8);

    // quad butterfly, PACKED: xor1 then xor2 on the 4 f2 pairs + scalar a8
    // (per-value add order identical to the scalar form -> absmax-0)
    a01 += dpp_f2<0xB1>(a01); a23 += dpp_f2<0xB1>(a23);
    a45 += dpp_f2<0xB1>(a45); a67 += dpp_f2<0xB1>(a67);
    a8  += dpp_f<0xB1>(a8);
    a01 += dpp_f2<0x4E>(a01); a23 += dpp_f2<0x4E>(a23);
    a45 += dpp_f2<0x4E>(a45); a67 += dpp_f2<0x4E>(a67);
    a8  += dpp_f<0x4E>(a8);

    // EARLY role select (3 of 9) from packed components; ror4/ror8 preserve
    // lane&3 (R12/R14-verified). {az,ar} stay packed for the ror stages.
    f2 zr;
    zr.x = (u == 0) ? a01.x : ((u == 1) ? a01.y : a23.x);   // az
    zr.y = (u == 0) ? a23.y : ((u == 1) ? a45.x : a45.y);   // ar
    float sh = (u == 0) ? a67.x : ((u == 1) ? a67.y : a8);  // h x-side

    // cross-quad rotate-accumulate (direction-free full sum over 4 quads)
    zr += dpp_f2<0x124>(zr); sh += dpp_f<0x124>(sh);
    zr += dpp_f2<0x128>(zr); sh += dpp_f<0x128>(sh);

    // gate chain (absmax-0 verified math; b0+b1 already inside az/ar)
    const float iz = fmaf(h2, wz[2], fmaf(h1, wz[1], fmaf(h0, wz[0], zr.x)));
    const float ir = fmaf(h2, wr[2], fmaf(h1, wr[1], fmaf(h0, wr[0], zr.y)));
    const float ih = fmaf(h2, wh[2], fmaf(h1, wh[1], fmaf(h0, wh[0], rbh)));
    const float z = fast_rcp(1.0f + fast_exp2(iz));
    const float r = fast_rcp(1.0f + fast_exp2(ir));
    const float t = fmaf(-2.0f, fast_rcp(1.0f + fast_exp2(fmaf(r, ih, sh))), 1.0f);
    const float hn = fmaf(z, hprev - t, t);
    hprev = hn;
    h0 = dpp_f<0x00>(hn);   // quad_perm [0,0,0,0]
    h1 = dpp_f<0x55>(hn);   // quad_perm [1,1,1,1]
    h2 = dpp_f<0xAA>(hn);   // quad_perm [2,2,2,2]
  };

  auto ld = [&](int sn) -> float4 { return pc[(size_t)sn * 16]; };

  X0 = ld(0); X1 = ld(1); X2 = ld(2); X3 = ld(3);
  X4 = ld(4); X5 = ld(5); X6 = ld(6); X7 = ld(7);

  // main loop: steps 0..247; raw (clamp-free) prefetch of sg+8..sg+15
  for (int sg = 0; sg < SS - 8; sg += 8) {
    step(X0); X0 = ld(sg + 8);
    step(X1); X1 = ld(sg + 9);
    step(X2); X2 = ld(sg + 10);
    step(X3); X3 = ld(sg + 11);
    step(X4); X4 = ld(sg + 12);
    step(X5); X5 = ld(sg + 13);
    step(X6); X6 = ld(sg + 14);
    step(X7); X7 = ld(sg + 15);
  }
  // epilogue: steps 248..255, no loads
  step(X0); step(X1); step(X2); step(X3);
  step(X4); step(X5); step(X6); step(X7);

  // Dense (3 -> 10) + softmax; only quad 0 of each chain row writes.
  if (fl < 4) {
    float lg[10];
#pragma unroll
    for (int j = 0; j < 10; ++j)
      lg[j] = dense_b[j] + h0 * dense_w[j] + h1 * dense_w[10 + j] + h2 * dense_w[20 + j];
    float m = lg[0];
#pragma unroll
    for (int j = 1; j < 10; ++j) m = fmaxf(m, lg[j]);
    float e[10];
    float ssum = 0.0f;
#pragma unroll
    for (int j = 0; j < 10; ++j) {
      e[j] = fast_exp2(1.4426950408889634f * (lg[j] - m));
      ssum += e[j];
    }
    const float inv = fast_rcp(ssum);
#pragma unroll
    for (int j = u; j < 10; j += 4) out[(size_t)c * 10 + j] = e[j] * inv;
  }
}

extern "C" void kernel_launch(void* const* d_in, const int* in_sizes, int n_in,
                              void* d_out, int out_size, void* d_ws, size_t ws_size,
                              hipStream_t stream) {
  const float* x      = (const float*)d_in[0];  // [4096,256,64]
  const float* kern   = (const float*)d_in[1];  // [64,9]
  const float* rkern  = (const float*)d_in[2];  // [3,9]
  const float* bias   = (const float*)d_in[3];  // [2,9]
  const float* dw     = (const float*)d_in[4];  // [3,10]
  const float* db     = (const float*)d_in[5];  // [10]
  float* out = (float*)d_out;

  // 4 chains x 16 lanes per 64-thread block; 1024 blocks -> 1 wave per SIMD
  // on all 1024 SIMDs.
  fused_gru_kernel<<<BB / 4, 64, 0, stream>>>(x, kern, rkern, bias, dw, db, out);
}

// Round 19
// 52.749 us; speedup vs baseline: 1.2730x; 1.2730x over previous
//
#include <hip/hip_runtime.h>

// Problem constants (from reference setup_inputs)
#define BB 4096   // batch
#define SS 256    // sequence length
#define FF 64     // features
#define GG 9      // 3*U gate width

#define NEG_LOG2E -1.4426950408889634f
#define TWO_LOG2E  2.8853900817779268f

typedef float f2 __attribute__((ext_vector_type(2)));

#if __has_builtin(__builtin_amdgcn_exp2f)
__device__ __forceinline__ float fast_exp2(float x) { return __builtin_amdgcn_exp2f(x); }
#else
__device__ __forceinline__ float fast_exp2(float x) { return exp2f(x); }
#endif
#if __has_builtin(__builtin_amdgcn_rcpf)
__device__ __forceinline__ float fast_rcp(float x) { return __builtin_amdgcn_rcpf(x); }
#else
__device__ __forceinline__ float fast_rcp(float x) { return 1.0f / x; }
#endif

// DPP helper: quad_perm (CTRL<0x100) and row ops (row_ror:N = 0x120+N).
// NOTE (R18 lesson): scalar `s += dpp_f<CTRL>(s)` fuses into a single
// v_add_f32 ... dpp VOP2 instruction. Do NOT pack these into f2/v_pk_add
// (VOP3P can't carry row-DPP modifiers -> compiler emits extra mov_dpp).
template <int CTRL>
__device__ __forceinline__ float dpp_f(float v) {
  return __int_as_float(
      __builtin_amdgcn_mov_dpp(__float_as_int(v), CTRL, 0xF, 0xF, true));
}

// -----------------------------------------------------------------------------
// Fully fused GRU — R19 = R17 champion restored (52.55us; R18's packed-f2
// reduce broke VOP2-DPP fusion and regressed to 67us).
// Final structure: 4 chains x 16 lanes per wave64, 1024 blocks = 1 wave on
// each of 1024 SIMDs; per-step: 1 float4 load (depth-8 clamp-free ring),
// 20 f2-packed projection FMAs, 18 fused dpp-add butterfly (xor1+xor2),
// early 3-of-9 role select, 6 fused dpp-add ror4/ror8, serial gate chain
// (6 trans ops), 3 quad_perm h-broadcasts. Last 8 steps peeled load-free.
// Evidence base: TLP variants (R8/R12/R16), reordering (R11), MFMA (R13),
// LDS staging (R7), feature-major (R15), packed reduce (R18) all regress;
// only instruction-diet rounds (R14, R17) gained. This is the floor of the
// 1-wave/SIMD serial-scan structure at ~430cy/step vs ~40us memory floor.
// -----------------------------------------------------------------------------
__global__ __launch_bounds__(64, 1) void fused_gru_kernel(
    const float* __restrict__ x,           // [B,S,F]
    const float* __restrict__ kernel_w,    // [F,9]
    const float* __restrict__ rec_kernel,  // [3,9]
    const float* __restrict__ bias,        // [2,9]
    const float* __restrict__ dense_w,     // [3,10]
    const float* __restrict__ dense_b,     // [10]
    float* __restrict__ out)               // [B,10]
{
  const int lane = threadIdx.x;        // 0..63
  const int fl   = lane & 15;          // feature-slot within the chain's row
  const int u    = lane & 3;           // gate-unit role within the quad
  const int uc   = (u < 3) ? u : 2;    // lane u==3: clamp unit role (benign)
  const int c    = blockIdx.x * 4 + (lane >> 4);   // chain (batch) id

  // ---- input-projection weights for this lane's 4 features (pre-scaled)
  f2 w01[4], w23[4], w45[4], w67[4];
  float w8[4];
#pragma unroll
  for (int e = 0; e < 4; ++e) {
    const float* kw = kernel_w + (fl * 4 + e) * GG;
    w01[e] = (f2){kw[0] * NEG_LOG2E, kw[1] * NEG_LOG2E};
    w23[e] = (f2){kw[2] * NEG_LOG2E, kw[3] * NEG_LOG2E};
    w45[e] = (f2){kw[4] * NEG_LOG2E, kw[5] * NEG_LOG2E};
    w67[e] = (f2){kw[6] * TWO_LOG2E, kw[7] * TWO_LOG2E};
    w8[e]  = kw[8] * TWO_LOG2E;
  }

  // input bias (+ recurrent bias folded for z/r gates — exact), pre-scaled
  // and SIXTEENTH'd (16-lane reduce restores exactly 1x).
  const float Q = 0.0625f;
  const f2 b01q = {(bias[0] + bias[GG + 0]) * NEG_LOG2E * Q,
                   (bias[1] + bias[GG + 1]) * NEG_LOG2E * Q};
  const f2 b23q = {(bias[2] + bias[GG + 2]) * NEG_LOG2E * Q,
                   (bias[3] + bias[GG + 3]) * NEG_LOG2E * Q};
  const f2 b45q = {(bias[4] + bias[GG + 4]) * NEG_LOG2E * Q,
                   (bias[5] + bias[GG + 5]) * NEG_LOG2E * Q};
  const f2 b67q = {bias[6] * TWO_LOG2E * Q, bias[7] * TWO_LOG2E * Q};
  const float b8q = bias[8] * TWO_LOG2E * Q;

  // recurrent weights for this lane's unit (pre-scaled); only the h-gate's
  // recurrent bias stays separate (it sits inside the r-multiplied term).
  float wz[3], wr[3], wh[3];
#pragma unroll
  for (int hh = 0; hh < 3; ++hh) {
    wz[hh] = rec_kernel[hh * GG + uc]     * NEG_LOG2E;
    wr[hh] = rec_kernel[hh * GG + 3 + uc] * NEG_LOG2E;
    wh[hh] = rec_kernel[hh * GG + 6 + uc] * TWO_LOG2E;
  }
  const float rbh = bias[GG + 6 + uc] * TWO_LOG2E;

  float h0 = 0.0f, h1 = 0.0f, h2 = 0.0f, hprev = 0.0f;

  // per-lane x pointer: row (c,s) = 16 float4s; this lane reads float4 #fl.
  const float4* pc = reinterpret_cast<const float4*>(x) + (size_t)c * SS * 16 + fl;

  // depth-8 register ring (32 VGPRs), named buffers, static indexing
  float4 X0, X1, X2, X3, X4, X5, X6, X7;

  auto step = [&](const float4 v) {
    // projection over this lane's 4 features (20 instrs, f2-packed)
    f2 a01 = b01q, a23 = b23q, a45 = b45q, a67 = b67q;
    float a8 = b8q;
    a01 = v.x * w01[0] + a01; a23 = v.x * w23[0] + a23;
    a45 = v.x * w45[0] + a45; a67 = v.x * w67[0] + a67;
    a8 = fmaf(v.x, w8[0], a8);
    a01 = v.y * w01[1] + a01; a23 = v.y * w23[1] + a23;
    a45 = v.y * w45[1] + a45; a67 = v.y * w67[1] + a67;
    a8 = fmaf(v.y, w8[1], a8);
    a01 = v.z * w01[2] + a01; a23 = v.z * w23[2] + a23;
    a45 = v.z * w45[2] + a45; a67 = v.z * w67[2] + a67;
    a8 = fmaf(v.z, w8[2], a8);
    a01 = v.w * w01[3] + a01; a23 = v.w * w23[3] + a23;
    a45 = v.w * w45[3] + a45; a67 = v.w * w67[3] + a67;
    a8 = fmaf(v.w, w8[3], a8);

    // quad butterfly: after xor1+xor2 every lane holds all 9 quad-sums
    // (each line = one fused v_add_f32 dpp)
    float s0 = a01.x, s1 = a01.y, s2 = a23.x, s3 = a23.y, s4 = a45.x,
          s5 = a45.y, s6 = a67.x, s7 = a67.y, s8 = a8;
    s0 += dpp_f<0xB1>(s0); s1 += dpp_f<0xB1>(s1); s2 += dpp_f<0xB1>(s2);
    s3 += dpp_f<0xB1>(s3); s4 += dpp_f<0xB1>(s4); s5 += dpp_f<0xB1>(s5);
    s6 += dpp_f<0xB1>(s6); s7 += dpp_f<0xB1>(s7); s8 += dpp_f<0xB1>(s8);
    s0 += dpp_f<0x4E>(s0); s1 += dpp_f<0x4E>(s1); s2 += dpp_f<0x4E>(s2);
    s3 += dpp_f<0x4E>(s3); s4 += dpp_f<0x4E>(s4); s5 += dpp_f<0x4E>(s5);
    s6 += dpp_f<0x4E>(s6); s7 += dpp_f<0x4E>(s7); s8 += dpp_f<0x4E>(s8);

    // EARLY role select (3 of 9): ror4/ror8 preserve lane&3 (R12/R14-verified)
    float az = (u == 0) ? s0 : ((u == 1) ? s1 : s2);
    float ar = (u == 0) ? s3 : ((u == 1) ? s4 : s5);
    float sh = (u == 0) ? s6 : ((u == 1) ? s7 : s8);

    // cross-quad rotate-accumulate (direction-free full sum over 4 quads)
    az += dpp_f<0x124>(az); ar += dpp_f<0x124>(ar); sh += dpp_f<0x124>(sh);
    az += dpp_f<0x128>(az); ar += dpp_f<0x128>(ar); sh += dpp_f<0x128>(sh);

    // gate chain (absmax-0 verified math; b0+b1 already inside az/ar)
    const float iz = fmaf(h2, wz[2], fmaf(h1, wz[1], fmaf(h0, wz[0], az)));
    const float ir = fmaf(h2, wr[2], fmaf(h1, wr[1], fmaf(h0, wr[0], ar)));
    const float ih = fmaf(h2, wh[2], fmaf(h1, wh[1], fmaf(h0, wh[0], rbh)));
    const float z = fast_rcp(1.0f + fast_exp2(iz));
    const float r = fast_rcp(1.0f + fast_exp2(ir));
    const float t = fmaf(-2.0f, fast_rcp(1.0f + fast_exp2(fmaf(r, ih, sh))), 1.0f);
    const float hn = fmaf(z, hprev - t, t);
    hprev = hn;
    h0 = dpp_f<0x00>(hn);   // quad_perm [0,0,0,0]
    h1 = dpp_f<0x55>(hn);   // quad_perm [1,1,1,1]
    h2 = dpp_f<0xAA>(hn);   // quad_perm [2,2,2,2]
  };

  auto ld = [&](int sn) -> float4 { return pc[(size_t)sn * 16]; };

  X0 = ld(0); X1 = ld(1); X2 = ld(2); X3 = ld(3);
  X4 = ld(4); X5 = ld(5); X6 = ld(6); X7 = ld(7);

  // main loop: steps 0..247; raw (clamp-free) prefetch of sg+8..sg+15
  for (int sg = 0; sg < SS - 8; sg += 8) {
    step(X0); X0 = ld(sg + 8);
    step(X1); X1 = ld(sg + 9);
    step(X2); X2 = ld(sg + 10);
    step(X3); X3 = ld(sg + 11);
    step(X4); X4 = ld(sg + 12);
    step(X5); X5 = ld(sg + 13);
    step(X6); X6 = ld(sg + 14);
    step(X7); X7 = ld(sg + 15);
  }
  // epilogue: steps 248..255, no loads
  step(X0); step(X1); step(X2); step(X3);
  step(X4); step(X5); step(X6); step(X7);

  // Dense (3 -> 10) + softmax; only quad 0 of each chain row writes.
  if (fl < 4) {
    float lg[10];
#pragma unroll
    for (int j = 0; j < 10; ++j)
      lg[j] = dense_b[j] + h0 * dense_w[j] + h1 * dense_w[10 + j] + h2 * dense_w[20 + j];
    float m = lg[0];
#pragma unroll
    for (int j = 1; j < 10; ++j) m = fmaxf(m, lg[j]);
    float e[10];
    float ssum = 0.0f;
#pragma unroll
    for (int j = 0; j < 10; ++j) {
      e[j] = fast_exp2(1.4426950408889634f * (lg[j] - m));
      ssum += e[j];
    }
    const float inv = fast_rcp(ssum);
#pragma unroll
    for (int j = u; j < 10; j += 4) out[(size_t)c * 10 + j] = e[j] * inv;
  }
}

extern "C" void kernel_launch(void* const* d_in, const int* in_sizes, int n_in,
                              void* d_out, int out_size, void* d_ws, size_t ws_size,
                              hipStream_t stream) {
  const float* x      = (const float*)d_in[0];  // [4096,256,64]
  const float* kern   = (const float*)d_in[1];  // [64,9]
  const float* rkern  = (const float*)d_in[2];  // [3,9]
  const float* bias   = (const float*)d_in[3];  // [2,9]
  const float* dw     = (const float*)d_in[4];  // [3,10]
  const float* db     = (const float*)d_in[5];  // [10]
  float* out = (float*)d_out;

  // 4 chains x 16 lanes per 64-thread block; 1024 blocks -> 1 wave per SIMD
  // on all 1024 SIMDs.
  fused_gru_kernel<<<BB / 4, 64, 0, stream>>>(x, kern, rkern, bias, dw, db, out);
}